// Round 6
// baseline (218.523 us; speedup 1.0000x reference)
//
#include <hip/hip_runtime.h>
#include <math.h>
#include <stdint.h>

// NetVLAD N=32, C=512, P=1024, K=64, ALPHA=100.
// R6: single fused kernel. Phase1: stream x once (split-bf16 3-pass MFMA
// logits) while banking bf16(x) into persistent LDS. In-block softmax.
// Phase2: LDS-only GEMM, atomicAdd f32 partials into out. Then correct+scale.
#define ALPHA 100.0f
#define EPSN 1e-12f

typedef __attribute__((ext_vector_type(8))) short bf16x8;
typedef __attribute__((ext_vector_type(4))) float f32x4;
typedef __attribute__((ext_vector_type(4))) unsigned int u32x4;

static __device__ __forceinline__ uint32_t f2bf(float f) {
    uint32_t u = __builtin_bit_cast(uint32_t, f);
    return (u + 0x7FFFu + ((u >> 16) & 1u)) >> 16;  // RNE
}
static __device__ __forceinline__ float bf2f(uint32_t b) {
    return __builtin_bit_cast(float, b << 16);
}

// ------- prep: v -> (vh, vl) bf16 split [k][c]; bias[k]; zero asum+knorm ----
__global__ __launch_bounds__(64) void prep_kernel(const float* __restrict__ v,
                                                  unsigned short* __restrict__ vh,
                                                  unsigned short* __restrict__ vl,
                                                  float* __restrict__ bias,
                                                  float* __restrict__ az) {
    int k = blockIdx.x, lane = threadIdx.x;
    az[k * 64 + lane] = 0.f;  // 4096 floats = asum(2048) + knorm(2048)
    const float* row = v + k * 512;
    float ssq = 0.f;
#pragma unroll
    for (int i = 0; i < 8; ++i) {
        int c = lane + 64 * i;
        float f = row[c];
        ssq = fmaf(f, f, ssq);
        uint32_t hi = f2bf(f);
        uint32_t lo = f2bf(f - bf2f(hi));
        vh[k * 512 + c] = (unsigned short)hi;
        vl[k * 512 + c] = (unsigned short)lo;
    }
#pragma unroll
    for (int off = 32; off > 0; off >>= 1) ssq += __shfl_xor(ssq, off, 64);
    if (lane == 0) bias[k] = -ALPHA * sqrtf(ssq);
}

// ======================= fused assign+vlad kernel ===========================
// grid 1024 = (n = bx&31, pblk = (bx>>5)*32); block 256 = 4 waves, wave = 16k
// k-strip x 32p. 16x16x32 MFMA throughout.
__global__ __launch_bounds__(256) void fused_kernel(
    const float* __restrict__ x, const unsigned short* __restrict__ vh,
    const unsigned short* __restrict__ vl, const float* __restrict__ bias,
    float* __restrict__ out, float* __restrict__ asum) {
    __shared__ uint32_t xs2[512 * 20];       // 40960B  bf16(x) pairs [c][p2], persistent
    __shared__ uint32_t xsp[32 * 34];        //  4352B  split (hi<<16|lo) [c][p], per chunk
    __shared__ uint32_t vhs[64 * 20];        //  5120B  vh tile [k][c/2]
    __shared__ uint32_t vls[64 * 20];        //  5120B
    __shared__ float Lbuf[64 * 34];          //  8704B  raw dot [k][p]
    __shared__ unsigned short a2s[64 * 40];  //  5120B  a*sinv bf16 [k][p], pitch 40
    __shared__ float sinv_s[32];
    __shared__ float bias_l[64];
    __shared__ float ssqx[4][8][4];          // wave x p-class x 4p partial ssq
    __shared__ float xch[32][8];             // softmax cross-seg exchange

    int tid = threadIdx.x, bx = blockIdx.x;
    int n = bx & 31, pblk = (bx >> 5) << 5;
    int l = tid & 63, w = tid >> 6;
    int kb = w << 4;                // wave's k-strip base
    int quad = l >> 4, m = l & 15;

    if (tid < 64) bias_l[tid] = bias[tid];

    int sc = tid >> 3;              // staging c-row 0..31
    int sp4 = (tid & 7) << 2;       // staging p-quad
    int vk = tid >> 2, vj = (tid & 3) << 3;

    const float* xg = x + (size_t)n * 524288 + pblk;
    const unsigned short* vhg = vh + vk * 512 + vj;
    const unsigned short* vlg = vl + vk * 512 + vj;

    f32x4 acc0, acc1;               // logits, two 16-p halves
#pragma unroll
    for (int r = 0; r < 4; ++r) { acc0[r] = 0.f; acc1[r] = 0.f; }
    float sq0 = 0.f, sq1 = 0.f, sq2 = 0.f, sq3 = 0.f;

    float4 px = *(const float4*)(xg + (size_t)sc * 1024 + sp4);
    u32x4 pvh = *(const u32x4*)vhg;
    u32x4 pvl = *(const u32x4*)vlg;

    // ---------------- phase 1: K-loop over 16 chunks of 32 c ----------------
    for (int ch = 0; ch < 16; ++ch) {
        __syncthreads();
        float4 v4 = px;
        sq0 = fmaf(v4.x, v4.x, sq0); sq1 = fmaf(v4.y, v4.y, sq1);
        sq2 = fmaf(v4.z, v4.z, sq2); sq3 = fmaf(v4.w, v4.w, sq3);
        uint32_t h0 = f2bf(v4.x), h1 = f2bf(v4.y), h2 = f2bf(v4.z), h3 = f2bf(v4.w);
        uint32_t lo0 = f2bf(v4.x - bf2f(h0)), lo1 = f2bf(v4.y - bf2f(h1));
        uint32_t lo2 = f2bf(v4.z - bf2f(h2)), lo3 = f2bf(v4.w - bf2f(h3));
        *(uint2*)&xsp[sc * 34 + sp4] = make_uint2((h0 << 16) | lo0, (h1 << 16) | lo1);
        *(uint2*)&xsp[sc * 34 + sp4 + 2] = make_uint2((h2 << 16) | lo2, (h3 << 16) | lo3);
        *(uint2*)&xs2[(ch * 32 + sc) * 20 + (sp4 >> 1)] =
            make_uint2(h0 | (h1 << 16), h2 | (h3 << 16));
        int vb = vk * 20 + (vj >> 1);
        *(uint2*)&vhs[vb] = make_uint2(pvh[0], pvh[1]);
        *(uint2*)&vhs[vb + 2] = make_uint2(pvh[2], pvh[3]);
        *(uint2*)&vls[vb] = make_uint2(pvl[0], pvl[1]);
        *(uint2*)&vls[vb + 2] = make_uint2(pvl[2], pvl[3]);
        __syncthreads();
        if (ch < 15) {
            int c0 = (ch + 1) << 5;
            px = *(const float4*)(xg + (size_t)(c0 + sc) * 1024 + sp4);
            pvh = *(const u32x4*)(vhg + c0);
            pvl = *(const u32x4*)(vlg + c0);
        }
        // A-frags: lane k = kb+m, contract c = quad*8+j
        int va = (kb + m) * 20 + (quad << 2);
        bf16x8 ah = *(const bf16x8*)&vhs[va];
        bf16x8 al = *(const bf16x8*)&vls[va];
#pragma unroll
        for (int f = 0; f < 2; ++f) {
            int p = (f << 4) + m;
            uint32_t wv[8];
#pragma unroll
            for (int j = 0; j < 8; ++j) wv[j] = xsp[(quad * 8 + j) * 34 + p];
            u32x4 bhp, blp;
#pragma unroll
            for (int q = 0; q < 4; ++q) {
                bhp[q] = (wv[2 * q] >> 16) | (wv[2 * q + 1] & 0xFFFF0000u);
                blp[q] = (wv[2 * q] & 0xFFFFu) | (wv[2 * q + 1] << 16);
            }
            bf16x8 bh = __builtin_bit_cast(bf16x8, bhp);
            bf16x8 bl = __builtin_bit_cast(bf16x8, blp);
            if (f == 0) {
                acc0 = __builtin_amdgcn_mfma_f32_16x16x32_bf16(ah, bh, acc0, 0, 0, 0);
                acc0 = __builtin_amdgcn_mfma_f32_16x16x32_bf16(ah, bl, acc0, 0, 0, 0);
                acc0 = __builtin_amdgcn_mfma_f32_16x16x32_bf16(al, bh, acc0, 0, 0, 0);
            } else {
                acc1 = __builtin_amdgcn_mfma_f32_16x16x32_bf16(ah, bh, acc1, 0, 0, 0);
                acc1 = __builtin_amdgcn_mfma_f32_16x16x32_bf16(ah, bl, acc1, 0, 0, 0);
                acc1 = __builtin_amdgcn_mfma_f32_16x16x32_bf16(al, bh, acc1, 0, 0, 0);
            }
        }
    }
    // ---------------- sinv + logits to LDS ----------------
#pragma unroll
    for (int mask = 8; mask <= 32; mask <<= 1) {
        sq0 += __shfl_xor(sq0, mask, 64); sq1 += __shfl_xor(sq1, mask, 64);
        sq2 += __shfl_xor(sq2, mask, 64); sq3 += __shfl_xor(sq3, mask, 64);
    }
    if (l < 8) {
        ssqx[w][l][0] = sq0; ssqx[w][l][1] = sq1;
        ssqx[w][l][2] = sq2; ssqx[w][l][3] = sq3;
    }
#pragma unroll
    for (int r = 0; r < 4; ++r) {
        Lbuf[(kb + quad * 4 + r) * 34 + m] = acc0[r];
        Lbuf[(kb + quad * 4 + r) * 34 + 16 + m] = acc1[r];
    }
    __syncthreads();
    if (tid < 32) {
        int pq = tid >> 2, cm = tid & 3;
        float s = ssqx[0][pq][cm] + ssqx[1][pq][cm] + ssqx[2][pq][cm] + ssqx[3][pq][cm];
        sinv_s[tid] = 1.0f / fmaxf(sqrtf(s), EPSN);
    }
    __syncthreads();
    // ---------------- softmax: thread = (p = tid&31, seg = tid>>5) ----------
    int p = tid & 31, seg = tid >> 5;
    float sv = sinv_s[p];
    float tA = 2.0f * ALPHA * sv;
    float d[8];
    float mx = -INFINITY;
#pragma unroll
    for (int j = 0; j < 8; ++j) {
        d[j] = fmaf(tA, Lbuf[(seg * 8 + j) * 34 + p], bias_l[seg * 8 + j]);
        mx = fmaxf(mx, d[j]);
    }
    xch[p][seg] = mx;
    __syncthreads();
#pragma unroll
    for (int q = 0; q < 8; ++q) mx = fmaxf(mx, xch[p][q]);
    float s = 0.f;
#pragma unroll
    for (int j = 0; j < 8; ++j) {
        d[j] = expf(d[j] - mx);
        s += d[j];
    }
    __syncthreads();
    xch[p][seg] = s;
    __syncthreads();
    s = 0.f;
#pragma unroll
    for (int q = 0; q < 8; ++q) s += xch[p][q];
    float rs = 1.0f / s;
    float a2f = rs * sv;
#pragma unroll
    for (int j = 0; j < 8; ++j) {
        a2s[(seg * 8 + j) * 40 + p] = (unsigned short)f2bf(d[j] * a2f);
        float red = d[j] * rs;
#pragma unroll
        for (int off = 1; off <= 16; off <<= 1) red += __shfl_xor(red, off, 64);
        if ((l & 31) == 0) atomicAdd(&asum[n * 64 + seg * 8 + j], red);
    }
    __syncthreads();  // a2s ready
    // ---------------- phase 2: D[k][c] partial = a2 . bf16(x) ---------------
    bf16x8 afr = *(const bf16x8*)&a2s[(kb + m) * 40 + (quad << 3)];  // invariant
    f32x4 zero4;
#pragma unroll
    for (int r = 0; r < 4; ++r) zero4[r] = 0.f;
    float* outb = out + (size_t)n * 32768 + (size_t)(kb + (quad << 2)) * 512;
#pragma unroll 4
    for (int cc = 0; cc < 32; ++cc) {
        int cr = (cc << 4) + m;
        u32x4 bp = *(const u32x4*)&xs2[cr * 20 + (quad << 2)];
        f32x4 dres = __builtin_amdgcn_mfma_f32_16x16x32_bf16(
            afr, __builtin_bit_cast(bf16x8, bp), zero4, 0, 0, 0);
        float* po = outb + cr;
        atomicAdd(po, dres[0]);
        atomicAdd(po + 512, dres[1]);
        atomicAdd(po + 1024, dres[2]);
        atomicAdd(po + 1536, dres[3]);
    }
}

// ------- correct: out -= asum*v per (n,k); knorm[n][k] = ssq (direct) -------
__global__ __launch_bounds__(64) void correct_kernel(
    float* __restrict__ out, const float* __restrict__ v,
    const float* __restrict__ asum, float* __restrict__ knorm) {
    int k = blockIdx.x, n = blockIdx.y, l = threadIdx.x;
    float as = asum[n * 64 + k];
    float* base = out + (size_t)n * 32768 + (size_t)k * 512;
    const float* vr = v + k * 512;
    float4 o0 = ((float4*)base)[l];
    float4 o1 = ((float4*)base)[l + 64];
    float4 v0 = ((const float4*)vr)[l];
    float4 v1 = ((const float4*)vr)[l + 64];
    o0.x = fmaf(-as, v0.x, o0.x); o0.y = fmaf(-as, v0.y, o0.y);
    o0.z = fmaf(-as, v0.z, o0.z); o0.w = fmaf(-as, v0.w, o0.w);
    o1.x = fmaf(-as, v1.x, o1.x); o1.y = fmaf(-as, v1.y, o1.y);
    o1.z = fmaf(-as, v1.z, o1.z); o1.w = fmaf(-as, v1.w, o1.w);
    ((float4*)base)[l] = o0;
    ((float4*)base)[l + 64] = o1;
    float ssq = o0.x * o0.x + o0.y * o0.y + o0.z * o0.z + o0.w * o0.w +
                o1.x * o1.x + o1.y * o1.y + o1.z * o1.z + o1.w * o1.w;
#pragma unroll
    for (int off = 32; off > 0; off >>= 1) ssq += __shfl_xor(ssq, off, 64);
    if (l == 0) knorm[n * 64 + k] = ssq;
}

// ------- scale: intra-norm (per k) * global norm (per n), in place ----------
__global__ __launch_bounds__(256) void scale_kernel(float* __restrict__ out,
                                                    const float* __restrict__ knorm) {
    int n = blockIdx.y;
    int sb = blockIdx.x;
    int tid = threadIdx.x;
    __shared__ float sc[64];
    __shared__ float tots;
    if (tid < 64) {
        float kn = knorm[n * 64 + tid];
        float nk = sqrtf(kn);
        float inv = 1.0f / fmaxf(nk, EPSN);
        sc[tid] = inv;
        float t = nk * inv;
        float t2 = t * t;
#pragma unroll
        for (int off = 32; off > 0; off >>= 1) t2 += __shfl_xor(t2, off, 64);
        if (tid == 0) tots = t2;
    }
    __syncthreads();
    float invt = 1.0f / fmaxf(sqrtf(tots), EPSN);
    float* base = out + (size_t)n * 32768 + sb * 4096;
#pragma unroll
    for (int i = 0; i < 16; ++i) {
        int idx = tid + 256 * i;
        int k = (sb * 4096 + idx) >> 9;
        base[idx] *= sc[k] * invt;
    }
}

extern "C" void kernel_launch(void* const* d_in, const int* in_sizes, int n_in,
                              void* d_out, int out_size, void* d_ws, size_t ws_size,
                              hipStream_t stream) {
    const float* x = (const float*)d_in[0];       // [32,512,32,32]
    const float* vocabs = (const float*)d_in[1];  // [64,512]
    float* out = (float*)d_out;                   // [32, 32768]
    char* ws = (char*)d_ws;
    unsigned short* vh = (unsigned short*)(ws);          // 65536 B
    unsigned short* vl = (unsigned short*)(ws + 65536);  // 65536 B
    float* bias  = (float*)(ws + 131072);                //   256 B
    float* asum  = (float*)(ws + 131328);                //  8192 B
    float* knorm = (float*)(ws + 139520);                //  8192 B (contiguous after asum)

    hipMemsetAsync(out, 0, (size_t)32 * 32768 * 4, stream);  // atomic accumulate target
    prep_kernel<<<64, 64, 0, stream>>>(vocabs, vh, vl, bias, asum);  // zeroes asum+knorm
    fused_kernel<<<1024, 256, 0, stream>>>(x, vh, vl, bias, out, asum);
    correct_kernel<<<dim3(64, 32), 64, 0, stream>>>(out, vocabs, asum, knorm);
    scale_kernel<<<dim3(8, 32), 256, 0, stream>>>(out, knorm);
}

// Round 7
// 137.003 us; speedup vs baseline: 1.5950x; 1.5950x over previous
//
#include <hip/hip_runtime.h>
#include <math.h>
#include <stdint.h>

// NetVLAD: N=32, C=512, P=1024, K=64, ALPHA=100. Split-bf16 MFMA.
// R7: R5 structure + CK-style lgkmcnt-only barrier and a one-barrier,
// deferred-stage, 2-chunk-lookahead K-loop pipeline (global loads are
// never drained by the barrier -> memory pipe stays busy through compute).
#define ALPHA 100.0f
#define EPSN 1e-12f

typedef __attribute__((ext_vector_type(8))) short bf16x8;
typedef __attribute__((ext_vector_type(16))) float f32x16;
typedef __attribute__((ext_vector_type(4))) unsigned int u32x4;

static __device__ __forceinline__ uint32_t f2bf(float f) {
    uint32_t u = __builtin_bit_cast(uint32_t, f);
    return (u + 0x7FFFu + ((u >> 16) & 1u)) >> 16;  // RNE
}
static __device__ __forceinline__ float bfhi(uint32_t u) {
    return __builtin_bit_cast(float, u & 0xFFFF0000u);
}
static __device__ __forceinline__ float bflo(uint32_t u) {
    return __builtin_bit_cast(float, u << 16);
}
static __device__ __forceinline__ uint32_t stage1(float f) {  // (hi<<16)|lo split
    uint32_t hi = f2bf(f);
    uint32_t lo = f2bf(f - __builtin_bit_cast(float, hi << 16));
    return (hi << 16) | lo;
}
static __device__ __forceinline__ uint32_t packbf(float a, float b) {
    return f2bf(a) | (f2bf(b) << 16);
}
// CK block_sync_lds(): barrier that waits LDS ops only; global loads
// stay in flight across it (no vmcnt drain).
static __device__ __forceinline__ void lds_barrier() {
    asm volatile("s_waitcnt lgkmcnt(0)\n\ts_barrier" ::: "memory");
}

// ------- prep: v -> (vh, vl) bf16 split [k][c]; bias[k]; zero asum+knorm ----
__global__ __launch_bounds__(64) void prep_kernel(const float* __restrict__ v,
                                                  unsigned short* __restrict__ vh,
                                                  unsigned short* __restrict__ vl,
                                                  float* __restrict__ bias,
                                                  float* __restrict__ az) {
    int k = blockIdx.x, lane = threadIdx.x;
    az[k * 64 + lane] = 0.f;  // 4096 floats = asum(2048) + knorm(2048)
    const float* row = v + k * 512;
    float ssq = 0.f;
#pragma unroll
    for (int i = 0; i < 8; ++i) {
        int c = lane + 64 * i;
        float f = row[c];
        ssq = fmaf(f, f, ssq);
        uint32_t hi = f2bf(f);
        uint32_t lo = f2bf(f - __builtin_bit_cast(float, hi << 16));
        vh[k * 512 + c] = (unsigned short)hi;
        vl[k * 512 + c] = (unsigned short)lo;
    }
#pragma unroll
    for (int off = 32; off > 0; off >>= 1) ssq += __shfl_xor(ssq, off, 64);
    if (lane == 0) bias[k] = -ALPHA * sqrtf(ssq);
}

// ======================= P1 assign helpers ==================================
static __device__ __forceinline__ void a_load(float4& pxa, float4& pxb,
                                              u32x4& pvh, u32x4& pvl,
                                              const float* xg,
                                              const unsigned short* vhg,
                                              const unsigned short* vlg,
                                              int c0, int xr, int xq) {
    pxa = *(const float4*)(xg + (size_t)(c0 + xr) * 1024 + xq);
    pxb = *(const float4*)(xg + (size_t)(c0 + xr + 16) * 1024 + xq);
    pvh = *(const u32x4*)(vhg + c0);
    pvl = *(const u32x4*)(vlg + c0);
}
static __device__ __forceinline__ void a_stage(uint32_t* xsb, uint32_t* vhsb,
                                               uint32_t* vlsb, const float4 pxa,
                                               const float4 pxb, const u32x4 pvh,
                                               const u32x4 pvl, int xr, int xq,
                                               int vk, int vj) {
    *(uint2*)&xsb[xr * 66 + xq] = make_uint2(stage1(pxa.x), stage1(pxa.y));
    *(uint2*)&xsb[xr * 66 + xq + 2] = make_uint2(stage1(pxa.z), stage1(pxa.w));
    *(uint2*)&xsb[(xr + 16) * 66 + xq] = make_uint2(stage1(pxb.x), stage1(pxb.y));
    *(uint2*)&xsb[(xr + 16) * 66 + xq + 2] = make_uint2(stage1(pxb.z), stage1(pxb.w));
    int vb = vk * 18 + (vj >> 1);
    *(uint2*)&vhsb[vb] = make_uint2(pvh[0], pvh[1]);
    *(uint2*)&vhsb[vb + 2] = make_uint2(pvh[2], pvh[3]);
    *(uint2*)&vlsb[vb] = make_uint2(pvl[0], pvl[1]);
    *(uint2*)&vlsb[vb + 2] = make_uint2(pvl[2], pvl[3]);
}
static __device__ __forceinline__ void a_compute(const uint32_t* xsb,
                                                 const uint32_t* vhsb,
                                                 const uint32_t* vlsb,
                                                 f32x16& acc, float& ssq,
                                                 int kh, int ph, int h, int cl) {
#pragma unroll
    for (int s = 0; s < 2; ++s) {
        int va = (32 * kh + cl) * 18 + 8 * s + 4 * h;
        uint2 a0 = *(const uint2*)&vhsb[va];
        uint2 a1 = *(const uint2*)&vhsb[va + 2];
        uint2 b0 = *(const uint2*)&vlsb[va];
        uint2 b1 = *(const uint2*)&vlsb[va + 2];
        u32x4 ahp, alp;
        ahp[0] = a0.x; ahp[1] = a0.y; ahp[2] = a1.x; ahp[3] = a1.y;
        alp[0] = b0.x; alp[1] = b0.y; alp[2] = b1.x; alp[3] = b1.y;
        uint32_t wv[8];
#pragma unroll
        for (int j = 0; j < 8; ++j)
            wv[j] = xsb[(16 * s + 8 * h + j) * 66 + 32 * ph + cl];
#pragma unroll
        for (int j = 0; j < 8; ++j) {
            float xv = bfhi(wv[j]) + bflo(wv[j]);
            ssq = fmaf(xv, xv, ssq);
        }
        u32x4 bhp, blp;
#pragma unroll
        for (int q = 0; q < 4; ++q) {
            bhp[q] = (wv[2 * q] >> 16) | (wv[2 * q + 1] & 0xFFFF0000u);
            blp[q] = (wv[2 * q] & 0xFFFFu) | (wv[2 * q + 1] << 16);
        }
        bf16x8 ah = __builtin_bit_cast(bf16x8, ahp);
        bf16x8 al = __builtin_bit_cast(bf16x8, alp);
        bf16x8 bh = __builtin_bit_cast(bf16x8, bhp);
        bf16x8 bl = __builtin_bit_cast(bf16x8, blp);
        acc = __builtin_amdgcn_mfma_f32_32x32x16_bf16(ah, bh, acc, 0, 0, 0);
        acc = __builtin_amdgcn_mfma_f32_32x32x16_bf16(ah, bl, acc, 0, 0, 0);
        acc = __builtin_amdgcn_mfma_f32_32x32x16_bf16(al, bh, acc, 0, 0, 0);
    }
}

// ================= P1 assign: D[k][p] = sum_c v[k][c]*x[c][p] ===============
// grid 512 = (n, 64-p block); block 256 = 4 waves (kh,ph), wave 32k x 32p.
__global__ __launch_bounds__(256) void assign_kernel(
    const float* __restrict__ x, const unsigned short* __restrict__ vh,
    const unsigned short* __restrict__ vl, const float* __restrict__ bias,
    unsigned short* __restrict__ aT, float* __restrict__ asum) {
    __shared__ uint32_t xs[2][32 * 66];
    __shared__ uint32_t vhs[2][64 * 18];
    __shared__ uint32_t vls[2][64 * 18];
    __shared__ float bias_l[64];
    __shared__ float xch[2][2][32];

    int tid = threadIdx.x, bx = blockIdx.x;
    int n = bx >> 4, pblk = (bx & 15) << 6;
    int l = tid & 63, w = tid >> 6;
    int kh = w & 1, ph = w >> 1;
    int h = l >> 5, cl = l & 31;

    if (tid < 64) bias_l[tid] = bias[tid];

    int xr = tid >> 4, xq = (tid & 15) << 2;
    int vk = tid >> 2, vj = (tid & 3) << 3;

    const float* xg = x + (size_t)n * 524288 + pblk;
    const unsigned short* vhg = vh + vk * 512 + vj;
    const unsigned short* vlg = vl + vk * 512 + vj;

    f32x16 acc;
#pragma unroll
    for (int r = 0; r < 16; ++r) acc[r] = 0.f;
    float ssq = 0.f;

    float4 pxa[2], pxb[2];
    u32x4 pvh[2], pvl[2];
    a_load(pxa[0], pxb[0], pvh[0], pvl[0], xg, vhg, vlg, 0, xr, xq);
    a_load(pxa[1], pxb[1], pvh[1], pvl[1], xg, vhg, vlg, 32, xr, xq);
    __syncthreads();  // bias_l visible; one full-drain barrier is fine here
    a_stage(xs[0], vhs[0], vls[0], pxa[0], pxb[0], pvh[0], pvl[0], xr, xq, vk, vj);
    lds_barrier();
#pragma unroll
    for (int cc = 0; cc < 8; ++cc) {
        // even ch = 2cc: stage ch+1 (set1) -> buf1; load ch+2 -> set0; compute buf0
        a_stage(xs[1], vhs[1], vls[1], pxa[1], pxb[1], pvh[1], pvl[1], xr, xq, vk, vj);
        if (cc < 7)
            a_load(pxa[0], pxb[0], pvh[0], pvl[0], xg, vhg, vlg, (2 * cc + 2) << 5, xr, xq);
        a_compute(xs[0], vhs[0], vls[0], acc, ssq, kh, ph, h, cl);
        lds_barrier();
        // odd ch = 2cc+1: stage ch+2 (set0) -> buf0; load ch+3 -> set1; compute buf1
        if (cc < 7) {
            a_stage(xs[0], vhs[0], vls[0], pxa[0], pxb[0], pvh[0], pvl[0], xr, xq, vk, vj);
            a_load(pxa[1], pxb[1], pvh[1], pvl[1], xg, vhg, vlg, (2 * cc + 3) << 5, xr, xq);
        }
        a_compute(xs[1], vhs[1], vls[1], acc, ssq, kh, ph, h, cl);
        lds_barrier();
    }
    // ---- epilogue: softmax over 64 k for each p-col (R5 verbatim) ----
    ssq += __shfl_xor(ssq, 32, 64);
    float sinv = 1.0f / fmaxf(sqrtf(ssq), EPSN);
    float twoAs = 2.0f * ALPHA * sinv;
    float e[16];
    float m = -INFINITY;
#pragma unroll
    for (int r = 0; r < 16; ++r) {
        int k = (r & 3) + 8 * (r >> 2) + 4 * h + 32 * kh;
        float lv = fmaf(twoAs, acc[r], bias_l[k]);
        e[r] = lv;
        m = fmaxf(m, lv);
    }
    m = fmaxf(m, __shfl_xor(m, 32, 64));
    __syncthreads();
    if (l < 32) xch[kh][ph][l] = m;
    __syncthreads();
    m = fmaxf(m, xch[1 - kh][ph][cl]);
    float ssum = 0.f;
#pragma unroll
    for (int r = 0; r < 16; ++r) {
        e[r] = expf(e[r] - m);
        ssum += e[r];
    }
    ssum += __shfl_xor(ssum, 32, 64);
    __syncthreads();
    if (l < 32) xch[kh][ph][l] = ssum;
    __syncthreads();
    ssum += xch[1 - kh][ph][cl];
    float rs = 1.0f / ssum;
    float a2s = rs * sinv;  // a2 = a*sinv (scale folded into a-side)
    unsigned short* aTn = aT + (size_t)n * 65536 + pblk + 32 * ph + cl;
#pragma unroll
    for (int r = 0; r < 16; ++r) {
        int k = (r & 3) + 8 * (r >> 2) + 4 * h + 32 * kh;
        aTn[(size_t)k * 1024] = (unsigned short)f2bf(e[r] * a2s);
        float red = e[r] * rs;
#pragma unroll
        for (int off = 1; off <= 16; off <<= 1) red += __shfl_xor(red, off, 64);
        if (cl == 0) atomicAdd(&asum[n * 64 + k], red);
    }
}

// ======================= P2 vlad helpers ====================================
static __device__ __forceinline__ void v_load(float4& qxa, float4& qxb,
                                              u32x4& qa0, u32x4& qa1,
                                              const float* xg,
                                              const unsigned short* ag, int p0) {
    qxa = *(const float4*)(xg + p0);
    qxb = *(const float4*)(xg + p0 + 32);
    qa0 = *(const u32x4*)(ag + p0);
    qa1 = *(const u32x4*)(ag + p0 + 8);
}
static __device__ __forceinline__ void v_stage(uint32_t* xtb, uint32_t* atb,
                                               const float4 qxa, const float4 qxb,
                                               const u32x4 qa0, const u32x4 qa1,
                                               int xr, int xq, int ak, int aj) {
    int xb = xr * 34 + (xq >> 1);
    *(uint2*)&xtb[xb] = make_uint2(packbf(qxa.x, qxa.y), packbf(qxa.z, qxa.w));
    *(uint2*)&xtb[xb + 16] = make_uint2(packbf(qxb.x, qxb.y), packbf(qxb.z, qxb.w));
    int ab = ak * 34 + (aj >> 1);
    *(uint2*)&atb[ab] = make_uint2(qa0[0], qa0[1]);
    *(uint2*)&atb[ab + 2] = make_uint2(qa0[2], qa0[3]);
    *(uint2*)&atb[ab + 4] = make_uint2(qa1[0], qa1[1]);
    *(uint2*)&atb[ab + 6] = make_uint2(qa1[2], qa1[3]);
}
static __device__ __forceinline__ void v_compute(const uint32_t* xtb,
                                                 const uint32_t* atb,
                                                 f32x16& acc, int kh, int h,
                                                 int cl) {
#pragma unroll
    for (int s = 0; s < 4; ++s) {
        int va = (32 * kh + cl) * 34 + 8 * s + 4 * h;
        uint2 f0 = *(const uint2*)&atb[va];
        uint2 f1 = *(const uint2*)&atb[va + 2];
        int vb = cl * 34 + 8 * s + 4 * h;
        uint2 g0 = *(const uint2*)&xtb[vb];
        uint2 g1 = *(const uint2*)&xtb[vb + 2];
        u32x4 afp, bfp;
        afp[0] = f0.x; afp[1] = f0.y; afp[2] = f1.x; afp[3] = f1.y;
        bfp[0] = g0.x; bfp[1] = g0.y; bfp[2] = g1.x; bfp[3] = g1.y;
        acc = __builtin_amdgcn_mfma_f32_32x32x16_bf16(
            __builtin_bit_cast(bf16x8, afp), __builtin_bit_cast(bf16x8, bfp),
            acc, 0, 0, 0);
    }
}

// ================= P2 vlad: D[k][c] = sum_p a2[k][p]*bf16(x)[c][p] ==========
// grid 512 = (n, 32-c block); block 256 = 4 waves (kh, p-parity).
__global__ __launch_bounds__(256) void vlad_kernel(
    const float* __restrict__ x, const unsigned short* __restrict__ aT,
    const float* __restrict__ asum, const float* __restrict__ vocabs,
    float* __restrict__ out, float* __restrict__ knorm) {
    __shared__ uint32_t xt[2][32 * 34];
    __shared__ uint32_t at[2][64 * 34];
    __shared__ float cmb[2][64][16];
    __shared__ float asum_l[64];

    int tid = threadIdx.x, bx = blockIdx.x;
    int n = bx >> 4, cb = (bx & 15) << 5;
    int l = tid & 63, w = tid >> 6;
    int kh = w & 1, ps = w >> 1;
    int h = l >> 5, cl = l & 31;

    if (tid < 64) asum_l[tid] = asum[n * 64 + tid];

    int xr = tid >> 3, xq = (tid & 7) << 2;
    int ak = tid >> 2, aj = (tid & 3) << 4;

    const float* xg = x + (size_t)n * 524288 + (size_t)(cb + xr) * 1024 + xq;
    const unsigned short* ag = aT + (size_t)n * 65536 + (size_t)ak * 1024 + aj;

    f32x16 acc;
#pragma unroll
    for (int r = 0; r < 16; ++r) acc[r] = 0.f;

    float4 qxa[2], qxb[2];
    u32x4 qa0[2], qa1[2];
    v_load(qxa[0], qxb[0], qa0[0], qa1[0], xg, ag, 0);
    v_load(qxa[1], qxb[1], qa0[1], qa1[1], xg, ag, 64);
    __syncthreads();  // asum_l visible
    v_stage(xt[0], at[0], qxa[0], qxb[0], qa0[0], qa1[0], xr, xq, ak, aj);
    lds_barrier();
#pragma unroll
    for (int cc = 0; cc < 8; ++cc) {
        // even ch = 2cc (computed by ps==0 waves)
        v_stage(xt[1], at[1], qxa[1], qxb[1], qa0[1], qa1[1], xr, xq, ak, aj);
        if (cc < 7)
            v_load(qxa[0], qxb[0], qa0[0], qa1[0], xg, ag, (2 * cc + 2) << 6);
        if (ps == 0) v_compute(xt[0], at[0], acc, kh, h, cl);
        lds_barrier();
        // odd ch = 2cc+1 (computed by ps==1 waves)
        if (cc < 7) {
            v_stage(xt[0], at[0], qxa[0], qxb[0], qa0[0], qa1[0], xr, xq, ak, aj);
            v_load(qxa[1], qxb[1], qa0[1], qa1[1], xg, ag, (2 * cc + 3) << 6);
        }
        if (ps == 1) v_compute(xt[1], at[1], acc, kh, h, cl);
        lds_barrier();
    }
    // ---- epilogue: parity combine, -asum*v, store, knorm (R5 verbatim) ----
    __syncthreads();
    if (ps == 1) {
#pragma unroll
        for (int r = 0; r < 16; ++r) cmb[kh][l][r] = acc[r];
    }
    __syncthreads();
    if (ps == 0) {
#pragma unroll
        for (int r = 0; r < 16; ++r) {
            int k = (r & 3) + 8 * (r >> 2) + 4 * h + 32 * kh;
            int c = cb + cl;
            float val = acc[r] + cmb[kh][l][r];
            val = fmaf(-asum_l[k], vocabs[k * 512 + c], val);
            out[(size_t)n * 32768 + (size_t)k * 512 + c] = val;
            float t2 = val * val;
#pragma unroll
            for (int off = 1; off <= 16; off <<= 1) t2 += __shfl_xor(t2, off, 64);
            if (cl == 0) atomicAdd(&knorm[n * 64 + k], t2);
        }
    }
}

// ---------------- scale: intra-norm (per k) * global norm (per n), in place -
__global__ __launch_bounds__(256) void scale_kernel(float* __restrict__ out,
                                                    const float* __restrict__ knorm) {
    int n = blockIdx.y;
    int sb = blockIdx.x;
    int tid = threadIdx.x;
    __shared__ float sc[64];
    __shared__ float tots;
    if (tid < 64) {
        float kn = knorm[n * 64 + tid];
        float nk = sqrtf(kn);
        float inv = 1.0f / fmaxf(nk, EPSN);
        sc[tid] = inv;
        float t = nk * inv;
        float t2 = t * t;
#pragma unroll
        for (int off = 32; off > 0; off >>= 1) t2 += __shfl_xor(t2, off, 64);
        if (tid == 0) tots = t2;
    }
    __syncthreads();
    float invt = 1.0f / fmaxf(sqrtf(tots), EPSN);
    float* base = out + (size_t)n * 32768 + sb * 4096;
#pragma unroll
    for (int i = 0; i < 16; ++i) {
        int idx = tid + 256 * i;
        int k = (sb * 4096 + idx) >> 9;
        base[idx] *= sc[k] * invt;
    }
}

extern "C" void kernel_launch(void* const* d_in, const int* in_sizes, int n_in,
                              void* d_out, int out_size, void* d_ws, size_t ws_size,
                              hipStream_t stream) {
    const float* x = (const float*)d_in[0];       // [32,512,32,32]
    const float* vocabs = (const float*)d_in[1];  // [64,512]
    float* out = (float*)d_out;                   // [32, 32768]
    char* ws = (char*)d_ws;
    unsigned short* vh = (unsigned short*)(ws);            // 65536 B
    unsigned short* vl = (unsigned short*)(ws + 65536);    // 65536 B
    float* bias  = (float*)(ws + 131072);                  //   256 B
    float* asum  = (float*)(ws + 131328);                  //  8192 B
    float* knorm = (float*)(ws + 139520);                  //  8192 B
    unsigned short* aT = (unsigned short*)(ws + 147712);   // 4 MB : a2 [n][k][p]

    prep_kernel<<<64, 64, 0, stream>>>(vocabs, vh, vl, bias, asum);  // zeroes asum+knorm
    assign_kernel<<<512, 256, 0, stream>>>(x, vh, vl, bias, aT, asum);
    vlad_kernel<<<512, 256, 0, stream>>>(x, aT, asum, vocabs, out, knorm);
    scale_kernel<<<dim3(8, 32), 256, 0, stream>>>(out, knorm);
}